// Round 1
// baseline (210.095 us; speedup 1.0000x reference)
//
#include <hip/hip_runtime.h>
#include <math.h>

#define THREADS 256
#define INV_SQRT2 0.70710678118654752440f

// ---- monotonic float<->uint key transform (ascending order preserved) ----
__device__ __forceinline__ unsigned f2key(float f) {
    unsigned u = __float_as_uint(f);
    return (u & 0x80000000u) ? ~u : (u | 0x80000000u);
}
__device__ __forceinline__ float key2f(unsigned k) {
    unsigned u = (k & 0x80000000u) ? (k & 0x7fffffffu) : ~k;
    return __uint_as_float(u);
}

__device__ __forceinline__ float gelu_erf(float v) {
    return 0.5f * v * (1.0f + erff(v * INV_SQRT2));
}

// One-block-cooperative selection: find bucket containing the kin-th smallest
// (1-indexed) among 256*chunk cumulative histogram bins. All threads get the
// same (bucket, krem). Requires blockDim.x == 256.
__device__ void block_select(const unsigned* __restrict__ hist, int chunk,
                             long long kin, unsigned* bucket_out, long long* krem_out) {
    __shared__ unsigned s_ps[256];
    __shared__ unsigned s_bucket;
    __shared__ unsigned s_krem;
    const int t = threadIdx.x;
    const unsigned* h = hist + (size_t)t * chunk;
    unsigned s = 0;
    for (int i = 0; i < chunk; ++i) s += h[i];
    s_ps[t] = s;
    __syncthreads();
    if (t == 0) {
        unsigned run = 0;
        for (int i = 0; i < 256; ++i) { unsigned c = s_ps[i]; s_ps[i] = run; run += c; }
    }
    __syncthreads();
    long long base = (long long)s_ps[t];
    for (int i = 0; i < chunk; ++i) {
        unsigned c = h[i];
        if (base < kin && kin <= base + (long long)c) {
            s_bucket = (unsigned)(t * chunk + i);
            s_krem = (unsigned)(kin - base);
        }
        base += (long long)c;
    }
    __syncthreads();
    *bucket_out = s_bucket;
    *krem_out = (long long)s_krem;
    __syncthreads();
}

// K1: fused GELU + high-8-bit histogram of monotonic keys.
__global__ void __launch_bounds__(THREADS) k_gelu_hist8(
    const float4* __restrict__ x, float4* __restrict__ out,
    unsigned* __restrict__ hist8, long long n4)
{
    __shared__ unsigned lh[256 * 4];  // 4 sub-copies, interleaved to spread banks
    for (int i = threadIdx.x; i < 256 * 4; i += THREADS) lh[i] = 0;
    __syncthreads();
    const int c = threadIdx.x & 3;
    const long long stride = (long long)gridDim.x * THREADS;
    for (long long i = (long long)blockIdx.x * THREADS + threadIdx.x; i < n4; i += stride) {
        float4 v = x[i];
        float4 g;
        g.x = gelu_erf(v.x);
        g.y = gelu_erf(v.y);
        g.z = gelu_erf(v.z);
        g.w = gelu_erf(v.w);
        out[i] = g;
        atomicAdd(&lh[((f2key(v.x) >> 24) << 2) + c], 1u);
        atomicAdd(&lh[((f2key(v.y) >> 24) << 2) + c], 1u);
        atomicAdd(&lh[((f2key(v.z) >> 24) << 2) + c], 1u);
        atomicAdd(&lh[((f2key(v.w) >> 24) << 2) + c], 1u);
    }
    __syncthreads();
    const int t = threadIdx.x;
    unsigned s = lh[t * 4] + lh[t * 4 + 1] + lh[t * 4 + 2] + lh[t * 4 + 3];
    if (s) atomicAdd(&hist8[t], s);
}

// K2/K3: 12-bit refinement histogram. stage 0: filter on top-8 == b1,
// bin = key[23:12]. stage 1: filter on top-20 == (b1<<12)|b2, bin = key[11:0].
__global__ void __launch_bounds__(THREADS) k_hist12(
    const float4* __restrict__ x, long long n4, long long k0,
    const unsigned* __restrict__ h8, const unsigned* __restrict__ h12a,
    unsigned* __restrict__ hist_out, int stage)
{
    __shared__ unsigned lh[4096];
    unsigned b1; long long k1;
    block_select(h8, 1, k0, &b1, &k1);
    unsigned matchval = b1;
    int matchshift = 24;
    if (stage == 1) {
        unsigned b2; long long k2;
        block_select(h12a, 16, k1, &b2, &k2);
        matchval = (b1 << 12) | b2;
        matchshift = 12;
    }
    for (int i = threadIdx.x; i < 4096; i += THREADS) lh[i] = 0;
    __syncthreads();
    const int binshift = matchshift - 12;
    const long long stride = (long long)gridDim.x * THREADS;
    for (long long i = (long long)blockIdx.x * THREADS + threadIdx.x; i < n4; i += stride) {
        float4 v = x[i];
        unsigned k;
        k = f2key(v.x); if ((k >> matchshift) == matchval) atomicAdd(&lh[(k >> binshift) & 0xFFFu], 1u);
        k = f2key(v.y); if ((k >> matchshift) == matchval) atomicAdd(&lh[(k >> binshift) & 0xFFFu], 1u);
        k = f2key(v.z); if ((k >> matchshift) == matchval) atomicAdd(&lh[(k >> binshift) & 0xFFFu], 1u);
        k = f2key(v.w); if ((k >> matchshift) == matchval) atomicAdd(&lh[(k >> binshift) & 0xFFFu], 1u);
    }
    __syncthreads();
    for (int i = threadIdx.x; i < 4096; i += THREADS) {
        unsigned s = lh[i];
        if (s) atomicAdd(&hist_out[i], s);
    }
}

// K4: every block re-derives the exact kth value from the three histograms
// (cheap), block 0 writes the scalar, all blocks stream x_saved.
__global__ void __launch_bounds__(THREADS) k_xsaved(
    const float4* __restrict__ x, float4* __restrict__ out, float* __restrict__ kth_out,
    const unsigned* __restrict__ h8, const unsigned* __restrict__ h12a,
    const unsigned* __restrict__ h12b, long long k0, long long n4)
{
    unsigned b1, b2, b3; long long k1, k2, k3;
    block_select(h8, 1, k0, &b1, &k1);
    block_select(h12a, 16, k1, &b2, &k2);
    block_select(h12b, 16, k2, &b3, &k3);
    const unsigned key = (b1 << 24) | (b2 << 12) | b3;
    const float kth = key2f(key);
    if (blockIdx.x == 0 && threadIdx.x == 0) *kth_out = kth;
    const long long stride = (long long)gridDim.x * THREADS;
    for (long long i = (long long)blockIdx.x * THREADS + threadIdx.x; i < n4; i += stride) {
        float4 v = x[i];
        float4 r;
        r.x = v.x > kth ? v.x : -10.0f;
        r.y = v.y > kth ? v.y : -10.0f;
        r.z = v.z > kth ? v.z : -10.0f;
        r.w = v.w > kth ? v.w : -10.0f;
        out[i] = r;
    }
}

extern "C" void kernel_launch(void* const* d_in, const int* in_sizes, int n_in,
                              void* d_out, int out_size, void* d_ws, size_t ws_size,
                              hipStream_t stream) {
    (void)n_in; (void)out_size; (void)ws_size;
    const float* x = (const float*)d_in[0];
    float* out = (float*)d_out;
    const long long n = (long long)in_sizes[0];      // 33,554,432
    const long long n4 = n / 4;
    const long long k0 = (long long)((double)n * 0.9);  // matches Python int(n*0.9)

    unsigned* h8   = (unsigned*)d_ws;       // 256 bins
    unsigned* h12a = h8 + 256;              // 4096 bins
    unsigned* h12b = h12a + 4096;           // 4096 bins
    hipMemsetAsync(d_ws, 0, (256 + 4096 + 4096) * sizeof(unsigned), stream);

    float* gelu_out   = out;            // [0, n)
    float* xsaved_out = out + n;        // [n, 2n)
    float* kth_out    = out + 2 * n;    // [2n]

    const int blocks = 2048;
    k_gelu_hist8<<<blocks, THREADS, 0, stream>>>((const float4*)x, (float4*)gelu_out, h8, n4);
    k_hist12<<<blocks, THREADS, 0, stream>>>((const float4*)x, n4, k0, h8, h12a, h12a, 0);
    k_hist12<<<blocks, THREADS, 0, stream>>>((const float4*)x, n4, k0, h8, h12a, h12b, 1);
    k_xsaved<<<blocks, THREADS, 0, stream>>>((const float4*)x, (float4*)xsaved_out, kth_out,
                                             h8, h12a, h12b, k0, n4);
}